// Round 8
// baseline (145.168 us; speedup 1.0000x reference)
//
#include <hip/hip_runtime.h>
#include <hip/hip_bf16.h>

#define BN 8192      // batch rows
#define MM 8199      // real rows (BN + 7 centers)
#define MP 8208      // padded to multiple of 16
#define HH 128       // feature dim
#define EE 256       // center embedding dim
#define GX 128       // i-blocks (64 rows each)
#define GY 16
#define NUM_HIST 7

typedef __attribute__((ext_vector_type(8))) short short8;   // 8 bf16 = 4 VGPRs
typedef __attribute__((ext_vector_type(4))) float floatx4;

// ============================================================================
// TRANSPOSED LAYOUT rnt: MFMA-fragment-order so every main_kernel load is a
// contiguous 1KB per wave.  For j-tile t (16 rows), k-block kblk (8 bf16),
// col (row-within-tile):  bf16 addr = t*2048 + kblk*128 + col*8.
// A wave's fragment kk load: rnt + t*2048 + kk*512 + lane*8  (lane=q*16+col,
// q*128+col*8 == lane*8)  -> lanes cover [0,1024) bytes contiguously.
// r7 MEASURED: this change alone took main 63.5 -> 43.3 us (-32%). The old
// row-major layout wasted half of every fetched line (~6 TB/s pattern bound).
// ============================================================================

// ---- prep kernel: fuses {zero tot/pos, centers GEMV, row-normalize+transpose}
// blocks 0..2047: 4 batch rows each (wave per row) + zero 8 floats of tot/pos.
// block 2048: curr_centers into LDS, then the 16 padded rows (zeros for c>=7).
__global__ __launch_bounds__(256)
void prep_kernel(const float* __restrict__ reps,
                 const int* __restrict__ labels,
                 const float* __restrict__ centers,
                 const float* __restrict__ fc_w,
                 const float* __restrict__ fc_b,
                 __hip_bfloat16* __restrict__ rnt,
                 int* __restrict__ labp,
                 float* __restrict__ tot) {  // pos = tot + BN (contiguous)
  const int wid = threadIdx.x >> 6, lane = threadIdx.x & 63;
  const int b = blockIdx.x;
  if (b < 2048) {
    if (threadIdx.x < 8) tot[b * 8 + threadIdx.x] = 0.f;   // zeroes tot+pos (16384 floats)
    const int r = b * 4 + wid;
    float2 v = ((const float2*)(reps + (size_t)r * HH))[lane];   // k = 2*lane, 2*lane+1
    float ss = v.x * v.x + v.y * v.y;
#pragma unroll
    for (int m = 1; m < 64; m <<= 1) ss += __shfl_xor(ss, m);
    float inv = 1.0f / fmaxf(sqrtf(ss), 1e-8f);
    __hip_bfloat162 h2;
    h2.x = __float2bfloat16(v.x * inv);
    h2.y = __float2bfloat16(v.y * inv);
    // transposed store: bf16 addr = (r>>4)*2048 + (lane>>2)*128 + (r&15)*8 + 2*(lane&3)
    size_t o = (size_t)(r >> 4) * 1024 + (lane >> 2) * 64 + (r & 15) * 4 + (lane & 3);
    ((__hip_bfloat162*)rnt)[o] = h2;
    if (lane == 0) labp[r] = labels[r];
  } else {
    // ---- block 2048: centers @ fc_w^T + fc_b  -> LDS, then padded rows
    __shared__ float currs[7 * HH];
    for (int o = threadIdx.x; o < 7 * HH; o += 256) {
      int c = o >> 7, h = o & 127;
      const float4* ce = (const float4*)(centers + c * EE);
      const float4* w  = (const float4*)(fc_w + h * EE);
      float s = 0.f;
#pragma unroll 4
      for (int j = 0; j < EE / 4; ++j) {
        float4 a = ce[j], bb = w[j];
        s += a.x * bb.x + a.y * bb.y + a.z * bb.z + a.w * bb.w;
      }
      currs[o] = s + fc_b[h];
    }
    __syncthreads();
    // rows 8192..8207 (j-tile 512): wave wid handles 4 rows; zeros for c>=7
    for (int k = 0; k < 4; ++k) {
      int c = wid * 4 + k;            // 0..15
      int r = BN + c;
      float2 v = make_float2(0.f, 0.f);
      if (c < 7) v = ((const float2*)(currs + c * HH))[lane];
      float ss = v.x * v.x + v.y * v.y;
#pragma unroll
      for (int m = 1; m < 64; m <<= 1) ss += __shfl_xor(ss, m);
      float inv = 1.0f / fmaxf(sqrtf(ss), 1e-8f);
      __hip_bfloat162 h2;
      h2.x = __float2bfloat16(v.x * inv);
      h2.y = __float2bfloat16(v.y * inv);
      size_t o = (size_t)(r >> 4) * 1024 + (lane >> 2) * 64 + (r & 15) * 4 + (lane & 3);
      ((__hip_bfloat162*)rnt)[o] = h2;
      if (lane == 0) labp[r] = (r < MM) ? r - BN : -1;
    }
  }
}

// ---- main kernel: per i-row, tot_i = sum_j e_ij (j!=i), pos_i = same over label match
// e_ij = exp2((cos_ij - 1) * (0.5/TEMP) * log2e)   [global-max shift cancels in ratio]
// Padded j-columns (rnt==0) contribute exactly exp2(-K2) each to tot; the loss
// kernel subtracts the exact constant 9*exp2(-K2). Padded labp=-1 never matches.
// Structure = round-7 measured form (coalesced transposed layout, 43.3 us).
// r8 change: __launch_bounds__(256,3) — combined VGPR+AGPR use is ~140/wave,
// cap becomes ~170 -> 3 waves/SIMD instead of 2, to cover the ~1Kcyc/iter of
// exposed L2 latency now that the load pattern is fixed.
// NOTE: NO __threadfence() anywhere — agent fences on gfx950 emit buffer_wbl2+
// buffer_inv (whole-L2 ops); 2048 of them tripled this kernel's duration (r3).
// NOTE: (256,5) cap=102 forced VGPR=48 + scratch spill (FETCH 410MB, r1).
// Tripwire for this round: FETCH >> 10MB or VGPR < 64 means the 170 cap spilled.
__global__ __launch_bounds__(256, 3)
void main_kernel(const __hip_bfloat16* __restrict__ rnt,
                 const int* __restrict__ labp,
                 float* __restrict__ tot,
                 float* __restrict__ pos) {
  __shared__ float red[128];   // [0..63]=tot for i-rows, [64..127]=pos
  const int lane = threadIdx.x & 63;
  const int wid  = threadIdx.x >> 6;
  const int q = lane >> 4, col = lane & 15;
  const int ibase = blockIdx.x * 64;
  const int chunk = (blockIdx.y << 2) | wid;   // 0..63
  const short* rns = (const short*)rnt;

  if (threadIdx.x < 128) red[threadIdx.x] = 0.f;

  // A fragments: lane holds A[m=col][k = kk*32 + q*8 + 0..7]
  // tile (blockIdx.x*4 + it), coalesced: base + kk*512 + lane*8
  short8 afrag[4][4];
#pragma unroll
  for (int it = 0; it < 4; ++it) {
    const short* base = rns + (size_t)(blockIdx.x * 4 + it) * 2048 + lane * 8;
    afrag[it][0] = *(const short8*)(base);
    afrag[it][1] = *(const short8*)(base + 512);
    afrag[it][2] = *(const short8*)(base + 1024);
    afrag[it][3] = *(const short8*)(base + 1536);
  }
  // i-labels for C/D layout rows: row = q*4 + r
  int labi[4][4];
#pragma unroll
  for (int it = 0; it < 4; ++it)
#pragma unroll
    for (int r = 0; r < 4; ++r)
      labi[it][r] = labp[ibase + it * 16 + q * 4 + r];

  float stot[4][4] = {};
  float spos[4][4] = {};
  const float K2 = 10.30496147f;  // 0.5/0.07 * log2(e)

  // B tiles: chunk strides 64 tiles (=131072 shorts) per step
  const short* bptr = rns + (size_t)chunk * 2048 + lane * 8;
  const int* lptr = labp + chunk * 16 + col;

  for (int jb = chunk * 16; jb < MP; jb += 1024) {
    // B fragments: lane holds B[k = kk*32 + q*8 + 0..7][n=col] — coalesced 1KB each
    short8 b0 = *(const short8*)(bptr);
    short8 b1 = *(const short8*)(bptr + 512);
    short8 b2 = *(const short8*)(bptr + 1024);
    short8 b3 = *(const short8*)(bptr + 1536);
    const int labj = *lptr;
    bptr += 64 * 2048;
    lptr += 1024;
#pragma unroll
    for (int it = 0; it < 4; ++it) {
      floatx4 acc = {0.f, 0.f, 0.f, 0.f};
      acc = __builtin_amdgcn_mfma_f32_16x16x32_bf16(afrag[it][0], b0, acc, 0, 0, 0);
      acc = __builtin_amdgcn_mfma_f32_16x16x32_bf16(afrag[it][1], b1, acc, 0, 0, 0);
      acc = __builtin_amdgcn_mfma_f32_16x16x32_bf16(afrag[it][2], b2, acc, 0, 0, 0);
      acc = __builtin_amdgcn_mfma_f32_16x16x32_bf16(afrag[it][3], b3, acc, 0, 0, 0);
      const bool isdiag = (jb == ibase + it * 16);  // wave-uniform
#pragma unroll
      for (int r = 0; r < 4; ++r) {
        // C/D layout: row = q*4 + r, col = lane&15 → i = ibase+it*16+q*4+r, j = jb+col
        float e = __builtin_amdgcn_exp2f(fmaf(acc[r], K2, -K2));  // raw v_exp_f32
        if (isdiag && (col == q * 4 + r)) e = 0.f;   // exclude diagonal j==i
        stot[it][r] += e;
        spos[it][r] += (labj == labi[it][r]) ? e : 0.f;
      }
    }
  }

  __syncthreads();   // red[] init visible

  // reduce across the 16 column-lanes, then across waves via LDS,
  // then ONE global atomic per i-row per block.
#pragma unroll
  for (int it = 0; it < 4; ++it)
#pragma unroll
    for (int r = 0; r < 4; ++r) {
      float tt = stot[it][r], pp = spos[it][r];
#pragma unroll
      for (int m = 1; m <= 8; m <<= 1) {
        tt += __shfl_xor(tt, m);
        pp += __shfl_xor(pp, m);
      }
      if (col == 0) {
        int li = it * 16 + q * 4 + r;   // 0..63 local i-row
        atomicAdd(&red[li], tt);
        atomicAdd(&red[64 + li], pp);
      }
    }
  __syncthreads();
  if (threadIdx.x < 64)       atomicAdd(&tot[ibase + threadIdx.x], red[threadIdx.x]);
  else if (threadIdx.x < 128) atomicAdd(&pos[ibase + threadIdx.x - 64], red[threadIdx.x]);
}

// ---- loss kernel: loss = sum(lv * (lv>0.3)) / (sum(lv>0.3) + eps),
//      lv = -log( ((pos/(tot-9*epad))/(hist[lab]+eps)) + eps )
__global__ __launch_bounds__(1024)
void loss_kernel(const float* __restrict__ tot,
                 const float* __restrict__ pos,
                 const int* __restrict__ labels,
                 float* __restrict__ out) {
  __shared__ int hist[NUM_HIST];
  __shared__ float s1[16], s2[16];
  const int tid = threadIdx.x;
  const int lane = tid & 63, wid = tid >> 6;
  if (tid < NUM_HIST) hist[tid] = 0;
  __syncthreads();
  // ballot-based histogram: 7 ballots per 1024-element stripe, no LDS contention
  int c0 = 0, c1 = 0, c2 = 0, c3 = 0, c4 = 0, c5 = 0, c6 = 0;
  for (int i = tid; i < BN; i += 1024) {
    int lab = labels[i];
    unsigned long long m0 = __ballot(lab == 0);
    unsigned long long m1 = __ballot(lab == 1);
    unsigned long long m2 = __ballot(lab == 2);
    unsigned long long m3 = __ballot(lab == 3);
    unsigned long long m4 = __ballot(lab == 4);
    unsigned long long m5 = __ballot(lab == 5);
    unsigned long long m6 = __ballot(lab == 6);
    if (lane == 0) {
      c0 += __popcll(m0); c1 += __popcll(m1); c2 += __popcll(m2);
      c3 += __popcll(m3); c4 += __popcll(m4); c5 += __popcll(m5);
      c6 += __popcll(m6);
    }
  }
  if (lane == 0) {
    atomicAdd(&hist[0], c0); atomicAdd(&hist[1], c1); atomicAdd(&hist[2], c2);
    atomicAdd(&hist[3], c3); atomicAdd(&hist[4], c4); atomicAdd(&hist[5], c5);
    atomicAdd(&hist[6], c6);
  }
  __syncthreads();
  const float K2 = 10.30496147f;
  const float epad9 = 9.0f * exp2f(-K2);   // padded-column excess in tot
  float lsum = 0.f, msum = 0.f;
  for (int i = tid; i < BN; i += 1024) {
    float t = tot[i] - epad9;
    float p = pos[i];
    float c = (float)hist[labels[i]];   // = sum(pos_mask*mask) exactly
    float pr = (p / t) / (c + 1e-8f);
    float lv = -logf(pr + 1e-8f);
    if (lv > 0.3f) { lsum += lv; msum += 1.f; }
  }
#pragma unroll
  for (int m = 1; m < 64; m <<= 1) {
    lsum += __shfl_xor(lsum, m);
    msum += __shfl_xor(msum, m);
  }
  if (lane == 0) { s1[wid] = lsum; s2[wid] = msum; }
  __syncthreads();
  if (wid == 0) {
    float a = (lane < 16) ? s1[lane] : 0.f;
    float b = (lane < 16) ? s2[lane] : 0.f;
#pragma unroll
    for (int m = 1; m < 16; m <<= 1) {
      a += __shfl_xor(a, m);
      b += __shfl_xor(b, m);
    }
    if (lane == 0) out[0] = a / (b + 1e-8f);
  }
}

extern "C" void kernel_launch(void* const* d_in, const int* in_sizes, int n_in,
                              void* d_out, int out_size, void* d_ws, size_t ws_size,
                              hipStream_t stream) {
  const float* reps    = (const float*)d_in[0];  // [8192,128]
  const int*   labels  = (const int*)d_in[1];    // [8192]
  const float* centers = (const float*)d_in[2];  // [7,256]
  const float* fc_w    = (const float*)d_in[3];  // [128,256]
  const float* fc_b    = (const float*)d_in[4];  // [128]
  float* out = (float*)d_out;

  char* ws = (char*)d_ws;
  int* labp   = (int*)(ws + 4096);                       // 8208*4
  __hip_bfloat16* rnt = (__hip_bfloat16*)(ws + 40960);   // 513 tiles * 4KB = 2101248 B
  float* tot = (float*)(ws + 40960 + 2101248);           // 8192*4
  float* pos = tot + BN;                                 // 8192*4 (contiguous after tot)

  prep_kernel<<<2049, 256, 0, stream>>>(reps, labels, centers, fc_w, fc_b, rnt, labp, tot);
  main_kernel<<<dim3(GX, GY), 256, 0, stream>>>(rnt, labp, tot, pos);
  loss_kernel<<<1, 1024, 0, stream>>>(tot, pos, labels, out);
}

// Round 9
// 135.433 us; speedup vs baseline: 1.0719x; 1.0719x over previous
//
#include <hip/hip_runtime.h>
#include <hip/hip_bf16.h>

#define BN 8192      // batch rows
#define MM 8199      // real rows (BN + 7 centers)
#define MP 8208      // padded to multiple of 16
#define HH 128       // feature dim
#define EE 256       // center embedding dim
#define GX2 64       // i-blocks (128 rows each)
#define GY 16        // j-chunks (32 tiles each; y=15 gets 33 incl. padded tile 512)
#define NUM_HIST 7

typedef __attribute__((ext_vector_type(8))) short short8;   // 8 bf16 = 4 VGPRs
typedef __attribute__((ext_vector_type(4))) float floatx4;

// ============================================================================
// TRANSPOSED LAYOUT rnt (r7, measured -32%): MFMA-fragment order. Tile t
// (16 rows), k-block kblk (8 bf16), col: bf16 addr = t*2048 + kblk*128 + col*8.
// Fragment kk load = base + t*2048 + kk*512 + lane*8 -> contiguous 1KB/wave.
//
// r9 restructure (canonical §5 GEMM anatomy):
//  - 128 i-rows/block, waves SPLIT i (wave w owns rows w*32..w*32+31,
//    afrag[2][4]=32 regs) and SHARE the j-tiles via LDS staging.
//  - B global traffic halves (263->131 MB); in-loop loads become ds_read_b128.
//  - grid 64x16=1024 blocks -> 4 blocks/CU; ~100 VGPR -> ~4 waves/SIMD.
//  - double-buffered 2x4KB LDS, stage(t+1) issued before compute(t),
//    one barrier per tile.
// History: r1 (256,5)=spill disaster; r3 __threadfence=L2-maintenance disaster;
// r4 occupancy-null, r5 VALU-null, r6 pipeline-null (all pre-coalescing);
// r8 (256,3) null (VGPR already below cap).
// ============================================================================

// ---- prep kernel: fuses {zero tot/pos, centers GEMV, row-normalize+transpose}
__global__ __launch_bounds__(256)
void prep_kernel(const float* __restrict__ reps,
                 const int* __restrict__ labels,
                 const float* __restrict__ centers,
                 const float* __restrict__ fc_w,
                 const float* __restrict__ fc_b,
                 __hip_bfloat16* __restrict__ rnt,
                 int* __restrict__ labp,
                 float* __restrict__ tot) {  // pos = tot + BN (contiguous)
  const int wid = threadIdx.x >> 6, lane = threadIdx.x & 63;
  const int b = blockIdx.x;
  if (b < 2048) {
    if (threadIdx.x < 8) tot[b * 8 + threadIdx.x] = 0.f;   // zeroes tot+pos (16384 floats)
    const int r = b * 4 + wid;
    float2 v = ((const float2*)(reps + (size_t)r * HH))[lane];   // k = 2*lane, 2*lane+1
    float ss = v.x * v.x + v.y * v.y;
#pragma unroll
    for (int m = 1; m < 64; m <<= 1) ss += __shfl_xor(ss, m);
    float inv = 1.0f / fmaxf(sqrtf(ss), 1e-8f);
    __hip_bfloat162 h2;
    h2.x = __float2bfloat16(v.x * inv);
    h2.y = __float2bfloat16(v.y * inv);
    // transposed store: bf16 addr = (r>>4)*2048 + (lane>>2)*128 + (r&15)*8 + 2*(lane&3)
    size_t o = (size_t)(r >> 4) * 1024 + (lane >> 2) * 64 + (r & 15) * 4 + (lane & 3);
    ((__hip_bfloat162*)rnt)[o] = h2;
    if (lane == 0) labp[r] = labels[r];
  } else {
    // ---- block 2048: centers @ fc_w^T + fc_b  -> LDS, then padded rows
    __shared__ float currs[7 * HH];
    for (int o = threadIdx.x; o < 7 * HH; o += 256) {
      int c = o >> 7, h = o & 127;
      const float4* ce = (const float4*)(centers + c * EE);
      const float4* w  = (const float4*)(fc_w + h * EE);
      float s = 0.f;
#pragma unroll 4
      for (int j = 0; j < EE / 4; ++j) {
        float4 a = ce[j], bb = w[j];
        s += a.x * bb.x + a.y * bb.y + a.z * bb.z + a.w * bb.w;
      }
      currs[o] = s + fc_b[h];
    }
    __syncthreads();
    // rows 8192..8207 (j-tile 512): wave wid handles 4 rows; zeros for c>=7
    for (int k = 0; k < 4; ++k) {
      int c = wid * 4 + k;            // 0..15
      int r = BN + c;
      float2 v = make_float2(0.f, 0.f);
      if (c < 7) v = ((const float2*)(currs + c * HH))[lane];
      float ss = v.x * v.x + v.y * v.y;
#pragma unroll
      for (int m = 1; m < 64; m <<= 1) ss += __shfl_xor(ss, m);
      float inv = 1.0f / fmaxf(sqrtf(ss), 1e-8f);
      __hip_bfloat162 h2;
      h2.x = __float2bfloat16(v.x * inv);
      h2.y = __float2bfloat16(v.y * inv);
      size_t o = (size_t)(r >> 4) * 1024 + (lane >> 2) * 64 + (r & 15) * 4 + (lane & 3);
      ((__hip_bfloat162*)rnt)[o] = h2;
      if (lane == 0) labp[r] = (r < MM) ? r - BN : -1;
    }
  }
}

// ---- main kernel: per i-row, tot_i = sum_j e_ij (j!=i), pos_i = same over label match
// e_ij = exp2((cos_ij - 1) * (0.5/TEMP) * log2e)   [global-max shift cancels in ratio]
// Padded j-columns (rnt==0) contribute exactly exp2(-K2) each to tot; the loss
// kernel subtracts the exact constant 9*exp2(-K2). Padded labp=-1 never matches.
__global__ __launch_bounds__(256, 2)
void main_kernel(const __hip_bfloat16* __restrict__ rnt,
                 const int* __restrict__ labp,
                 float* __restrict__ tot,
                 float* __restrict__ pos) {
  __shared__ short lbuf[2][2048];    // double-buffered 4KB j-tile
  const int lane = threadIdx.x & 63;
  const int w    = threadIdx.x >> 6;       // wave id: owns i-rows [w*32, w*32+32)
  const int q = lane >> 4, col = lane & 15;
  const int ibase = blockIdx.x * 128;
  const short* rns = (const short*)rnt;

  // A fragments for this wave's two i-tiles: Ti = bx*8 + w*2 + it
  short8 afrag[2][4];
  int tix[2];
#pragma unroll
  for (int it = 0; it < 2; ++it) {
    tix[it] = blockIdx.x * 8 + w * 2 + it;
    const short* base = rns + (size_t)tix[it] * 2048 + lane * 8;
    afrag[it][0] = *(const short8*)(base);
    afrag[it][1] = *(const short8*)(base + 512);
    afrag[it][2] = *(const short8*)(base + 1024);
    afrag[it][3] = *(const short8*)(base + 1536);
  }
  // i-labels for C/D layout rows: row = q*4 + r
  int labi[2][4];
#pragma unroll
  for (int it = 0; it < 2; ++it)
#pragma unroll
    for (int r = 0; r < 4; ++r)
      labi[it][r] = labp[ibase + (w * 2 + it) * 16 + q * 4 + r];

  float stot[2][4] = {};
  float spos[2][4] = {};
  const float K2 = 10.30496147f;  // 0.5/0.07 * log2(e)

  const int t0 = blockIdx.y * 32;
  const int nt = (blockIdx.y == GY - 1) ? 33 : 32;   // y=15 also owns padded tile 512

  // stage tile t0 into buf 0 (256 threads x dwordx4 = 4KB, coalesced)
  *(short8*)&lbuf[0][threadIdx.x * 8] =
      *(const short8*)(rns + (size_t)t0 * 2048 + threadIdx.x * 8);
  __syncthreads();

  for (int s = 0; s < nt; ++s) {
    const int cur = s & 1;
    const int t = t0 + s;
    // issue next tile's stage FIRST (global latency hides under compute)
    if (s + 1 < nt)
      *(short8*)&lbuf[cur ^ 1][threadIdx.x * 8] =
          *(const short8*)(rns + (size_t)(t + 1) * 2048 + threadIdx.x * 8);

    // B fragments from LDS (conflict-free contiguous ds_read_b128)
    const short* lb = &lbuf[cur][0];
    short8 b0 = *(const short8*)(lb + lane * 8);
    short8 b1 = *(const short8*)(lb + 512 + lane * 8);
    short8 b2 = *(const short8*)(lb + 1024 + lane * 8);
    short8 b3 = *(const short8*)(lb + 1536 + lane * 8);
    const int labj = labp[t * 16 + col];

#pragma unroll
    for (int it = 0; it < 2; ++it) {
      floatx4 acc = {0.f, 0.f, 0.f, 0.f};
      acc = __builtin_amdgcn_mfma_f32_16x16x32_bf16(afrag[it][0], b0, acc, 0, 0, 0);
      acc = __builtin_amdgcn_mfma_f32_16x16x32_bf16(afrag[it][1], b1, acc, 0, 0, 0);
      acc = __builtin_amdgcn_mfma_f32_16x16x32_bf16(afrag[it][2], b2, acc, 0, 0, 0);
      acc = __builtin_amdgcn_mfma_f32_16x16x32_bf16(afrag[it][3], b3, acc, 0, 0, 0);
      const bool isdiag = (t == tix[it]);  // wave-uniform
#pragma unroll
      for (int r = 0; r < 4; ++r) {
        // C/D layout: row = q*4 + r, col = lane&15 → i = tix*16+q*4+r, j = t*16+col
        float e = __builtin_amdgcn_exp2f(fmaf(acc[r], K2, -K2));  // raw v_exp_f32
        if (isdiag && (col == q * 4 + r)) e = 0.f;   // exclude diagonal j==i
        stot[it][r] += e;
        spos[it][r] += (labj == labi[it][r]) ? e : 0.f;
      }
    }
    __syncthreads();   // stage(s+1) visible; all reads of cur done before overwrite
  }

  // reduce across the 16 column-lanes, then one atomic per i-row per block
  // (waves own disjoint rows -> no cross-wave reduction needed)
#pragma unroll
  for (int it = 0; it < 2; ++it)
#pragma unroll
    for (int r = 0; r < 4; ++r) {
      float tt = stot[it][r], pp = spos[it][r];
#pragma unroll
      for (int m = 1; m <= 8; m <<= 1) {
        tt += __shfl_xor(tt, m);
        pp += __shfl_xor(pp, m);
      }
      if (col == 0) {
        int i = ibase + (w * 2 + it) * 16 + q * 4 + r;
        atomicAdd(&tot[i], tt);
        atomicAdd(&pos[i], pp);
      }
    }
}

// ---- loss kernel: loss = sum(lv * (lv>0.3)) / (sum(lv>0.3) + eps),
//      lv = -log( ((pos/(tot-9*epad))/(hist[lab]+eps)) + eps )
__global__ __launch_bounds__(1024)
void loss_kernel(const float* __restrict__ tot,
                 const float* __restrict__ pos,
                 const int* __restrict__ labels,
                 float* __restrict__ out) {
  __shared__ int hist[NUM_HIST];
  __shared__ float s1[16], s2[16];
  const int tid = threadIdx.x;
  const int lane = tid & 63, wid = tid >> 6;
  if (tid < NUM_HIST) hist[tid] = 0;
  __syncthreads();
  // ballot-based histogram: 7 ballots per 1024-element stripe, no LDS contention
  int c0 = 0, c1 = 0, c2 = 0, c3 = 0, c4 = 0, c5 = 0, c6 = 0;
  for (int i = tid; i < BN; i += 1024) {
    int lab = labels[i];
    unsigned long long m0 = __ballot(lab == 0);
    unsigned long long m1 = __ballot(lab == 1);
    unsigned long long m2 = __ballot(lab == 2);
    unsigned long long m3 = __ballot(lab == 3);
    unsigned long long m4 = __ballot(lab == 4);
    unsigned long long m5 = __ballot(lab == 5);
    unsigned long long m6 = __ballot(lab == 6);
    if (lane == 0) {
      c0 += __popcll(m0); c1 += __popcll(m1); c2 += __popcll(m2);
      c3 += __popcll(m3); c4 += __popcll(m4); c5 += __popcll(m5);
      c6 += __popcll(m6);
    }
  }
  if (lane == 0) {
    atomicAdd(&hist[0], c0); atomicAdd(&hist[1], c1); atomicAdd(&hist[2], c2);
    atomicAdd(&hist[3], c3); atomicAdd(&hist[4], c4); atomicAdd(&hist[5], c5);
    atomicAdd(&hist[6], c6);
  }
  __syncthreads();
  const float K2 = 10.30496147f;
  const float epad9 = 9.0f * exp2f(-K2);   // padded-column excess in tot
  float lsum = 0.f, msum = 0.f;
  for (int i = tid; i < BN; i += 1024) {
    float t = tot[i] - epad9;
    float p = pos[i];
    float c = (float)hist[labels[i]];   // = sum(pos_mask*mask) exactly
    float pr = (p / t) / (c + 1e-8f);
    float lv = -logf(pr + 1e-8f);
    if (lv > 0.3f) { lsum += lv; msum += 1.f; }
  }
#pragma unroll
  for (int m = 1; m < 64; m <<= 1) {
    lsum += __shfl_xor(lsum, m);
    msum += __shfl_xor(msum, m);
  }
  if (lane == 0) { s1[wid] = lsum; s2[wid] = msum; }
  __syncthreads();
  if (wid == 0) {
    float a = (lane < 16) ? s1[lane] : 0.f;
    float b = (lane < 16) ? s2[lane] : 0.f;
#pragma unroll
    for (int m = 1; m < 16; m <<= 1) {
      a += __shfl_xor(a, m);
      b += __shfl_xor(b, m);
    }
    if (lane == 0) out[0] = a / (b + 1e-8f);
  }
}

extern "C" void kernel_launch(void* const* d_in, const int* in_sizes, int n_in,
                              void* d_out, int out_size, void* d_ws, size_t ws_size,
                              hipStream_t stream) {
  const float* reps    = (const float*)d_in[0];  // [8192,128]
  const int*   labels  = (const int*)d_in[1];    // [8192]
  const float* centers = (const float*)d_in[2];  // [7,256]
  const float* fc_w    = (const float*)d_in[3];  // [128,256]
  const float* fc_b    = (const float*)d_in[4];  // [128]
  float* out = (float*)d_out;

  char* ws = (char*)d_ws;
  int* labp   = (int*)(ws + 4096);                       // 8208*4
  __hip_bfloat16* rnt = (__hip_bfloat16*)(ws + 40960);   // 513 tiles * 4KB = 2101248 B
  float* tot = (float*)(ws + 40960 + 2101248);           // 8192*4
  float* pos = tot + BN;                                 // 8192*4 (contiguous after tot)

  prep_kernel<<<2049, 256, 0, stream>>>(reps, labels, centers, fc_w, fc_b, rnt, labp, tot);
  main_kernel<<<dim3(GX2, GY), 256, 0, stream>>>(rnt, labp, tot, pos);
  loss_kernel<<<1, 1024, 0, stream>>>(tot, pos, labels, out);
}

// Round 10
// 131.058 us; speedup vs baseline: 1.1077x; 1.0334x over previous
//
#include <hip/hip_runtime.h>
#include <hip/hip_bf16.h>

#define BN 8192      // batch rows
#define MM 8199      // real rows (BN + 7 centers)
#define MP 8208      // padded to multiple of 16
#define HH 128       // feature dim
#define EE 256       // center embedding dim
#define GX2 64       // i-blocks (128 rows each)
#define GY 16        // j-chunks (32 tiles each; y=15 also does padded tile 512)
#define NUM_HIST 7

typedef __attribute__((ext_vector_type(8))) short short8;   // 8 bf16 = 4 VGPRs
typedef __attribute__((ext_vector_type(4))) float floatx4;

// ============================================================================
// TRANSPOSED LAYOUT rnt (r7, measured -32%): MFMA-fragment order. Tile t
// (16 rows), k-block kblk (8 bf16), col: bf16 addr = t*2048 + kblk*128 + col*8.
// Fragment kk load = base + t*2048 + kk*512 + lane*8 -> contiguous 1KB/wave.
//
// r9 (measured ~36us): 128 i-rows/block, waves split i, B shared via LDS
// double-buffer, 1 barrier/tile. r10 edits (T14 + pair-staging + diag hoist):
//  - stage split: global->named regs BEFORE compute, ds_write AFTER compute,
//    barrier last (latency hides under MFMA+epilogue, no early vmcnt drain)
//  - 2 tiles per barrier (16 barriers + global-direct tail vs 33)
//  - diagonal exclusion hoisted to wave-uniform post-subtract (saves ~2
//    VALU/element on 67M elements)
// History: r1 (256,5)=spill disaster; r3 __threadfence=L2-maintenance disaster;
// r4 occupancy-null, r5 VALU-null, r6 pipeline-null (all pre-coalescing);
// r8 (256,3) null (VGPR already below cap).
// ============================================================================

// ---- prep kernel: fuses {zero tot/pos, centers GEMV, row-normalize+transpose}
__global__ __launch_bounds__(256)
void prep_kernel(const float* __restrict__ reps,
                 const int* __restrict__ labels,
                 const float* __restrict__ centers,
                 const float* __restrict__ fc_w,
                 const float* __restrict__ fc_b,
                 __hip_bfloat16* __restrict__ rnt,
                 int* __restrict__ labp,
                 float* __restrict__ tot) {  // pos = tot + BN (contiguous)
  const int wid = threadIdx.x >> 6, lane = threadIdx.x & 63;
  const int b = blockIdx.x;
  if (b < 2048) {
    if (threadIdx.x < 8) tot[b * 8 + threadIdx.x] = 0.f;   // zeroes tot+pos (16384 floats)
    const int r = b * 4 + wid;
    float2 v = ((const float2*)(reps + (size_t)r * HH))[lane];   // k = 2*lane, 2*lane+1
    float ss = v.x * v.x + v.y * v.y;
#pragma unroll
    for (int m = 1; m < 64; m <<= 1) ss += __shfl_xor(ss, m);
    float inv = 1.0f / fmaxf(sqrtf(ss), 1e-8f);
    __hip_bfloat162 h2;
    h2.x = __float2bfloat16(v.x * inv);
    h2.y = __float2bfloat16(v.y * inv);
    // transposed store: bf16 addr = (r>>4)*2048 + (lane>>2)*128 + (r&15)*8 + 2*(lane&3)
    size_t o = (size_t)(r >> 4) * 1024 + (lane >> 2) * 64 + (r & 15) * 4 + (lane & 3);
    ((__hip_bfloat162*)rnt)[o] = h2;
    if (lane == 0) labp[r] = labels[r];
  } else {
    // ---- block 2048: centers @ fc_w^T + fc_b  -> LDS, then padded rows
    __shared__ float currs[7 * HH];
    for (int o = threadIdx.x; o < 7 * HH; o += 256) {
      int c = o >> 7, h = o & 127;
      const float4* ce = (const float4*)(centers + c * EE);
      const float4* w  = (const float4*)(fc_w + h * EE);
      float s = 0.f;
#pragma unroll 4
      for (int j = 0; j < EE / 4; ++j) {
        float4 a = ce[j], bb = w[j];
        s += a.x * bb.x + a.y * bb.y + a.z * bb.z + a.w * bb.w;
      }
      currs[o] = s + fc_b[h];
    }
    __syncthreads();
    // rows 8192..8207 (j-tile 512): wave wid handles 4 rows; zeros for c>=7
    for (int k = 0; k < 4; ++k) {
      int c = wid * 4 + k;            // 0..15
      int r = BN + c;
      float2 v = make_float2(0.f, 0.f);
      if (c < 7) v = ((const float2*)(currs + c * HH))[lane];
      float ss = v.x * v.x + v.y * v.y;
#pragma unroll
      for (int m = 1; m < 64; m <<= 1) ss += __shfl_xor(ss, m);
      float inv = 1.0f / fmaxf(sqrtf(ss), 1e-8f);
      __hip_bfloat162 h2;
      h2.x = __float2bfloat16(v.x * inv);
      h2.y = __float2bfloat16(v.y * inv);
      size_t o = (size_t)(r >> 4) * 1024 + (lane >> 2) * 64 + (r & 15) * 4 + (lane & 3);
      ((__hip_bfloat162*)rnt)[o] = h2;
      if (lane == 0) labp[r] = (r < MM) ? r - BN : -1;
    }
  }
}

// ---- main kernel: per i-row, tot_i = sum_j e_ij (j!=i), pos_i = same over label match
// e_ij = exp2((cos_ij - 1) * (0.5/TEMP) * log2e)   [global-max shift cancels in ratio]
// Padded j-columns (rnt==0) contribute exactly exp2(-K2) each to tot; the loss
// kernel subtracts the exact constant 9*exp2(-K2). Padded labp=-1 never matches.
__global__ __launch_bounds__(256, 2)
void main_kernel(const __hip_bfloat16* __restrict__ rnt,
                 const int* __restrict__ labp,
                 float* __restrict__ tot,
                 float* __restrict__ pos) {
  __shared__ short lbuf[2][4096];    // double-buffered 8KB tile-PAIR
  const int lane = threadIdx.x & 63;
  const int w    = threadIdx.x >> 6;       // wave id: owns i-rows [w*32, w*32+32)
  const int q = lane >> 4, col = lane & 15;
  const int ibase = blockIdx.x * 128;
  const short* rns = (const short*)rnt;

  // A fragments for this wave's two i-tiles: Ti = bx*8 + w*2 + it
  short8 afrag[2][4];
  int tix[2];
#pragma unroll
  for (int it = 0; it < 2; ++it) {
    tix[it] = blockIdx.x * 8 + w * 2 + it;
    const short* base = rns + (size_t)tix[it] * 2048 + lane * 8;
    afrag[it][0] = *(const short8*)(base);
    afrag[it][1] = *(const short8*)(base + 512);
    afrag[it][2] = *(const short8*)(base + 1024);
    afrag[it][3] = *(const short8*)(base + 1536);
  }
  // i-labels for C/D layout rows: row = q*4 + r
  int labi[2][4];
#pragma unroll
  for (int it = 0; it < 2; ++it)
#pragma unroll
    for (int r = 0; r < 4; ++r)
      labi[it][r] = labp[ibase + (w * 2 + it) * 16 + q * 4 + r];

  float stot[2][4] = {};
  float spos[2][4] = {};
  const float K2 = 10.30496147f;  // 0.5/0.07 * log2(e)

  // accumulate one j-tile given its 4 B fragments; diagonal handled by
  // wave-uniform post-subtract (taken for <=2 tiles per wave total).
  auto accum = [&](short8 b0, short8 b1, short8 b2, short8 b3, int t, int labj) {
#pragma unroll
    for (int it = 0; it < 2; ++it) {
      floatx4 acc = {0.f, 0.f, 0.f, 0.f};
      acc = __builtin_amdgcn_mfma_f32_16x16x32_bf16(afrag[it][0], b0, acc, 0, 0, 0);
      acc = __builtin_amdgcn_mfma_f32_16x16x32_bf16(afrag[it][1], b1, acc, 0, 0, 0);
      acc = __builtin_amdgcn_mfma_f32_16x16x32_bf16(afrag[it][2], b2, acc, 0, 0, 0);
      acc = __builtin_amdgcn_mfma_f32_16x16x32_bf16(afrag[it][3], b3, acc, 0, 0, 0);
      float ev[4];
#pragma unroll
      for (int r = 0; r < 4; ++r) {
        // C/D layout: row = q*4 + r, col = lane&15 → i = tix*16+q*4+r, j = t*16+col
        float e = __builtin_amdgcn_exp2f(fmaf(acc[r], K2, -K2));  // raw v_exp_f32
        ev[r] = e;
        stot[it][r] += e;
        spos[it][r] += (labj == labi[it][r]) ? e : 0.f;
      }
      if (t == tix[it]) {          // wave-uniform diagonal fix-up
#pragma unroll
        for (int r = 0; r < 4; ++r)
          if (col == q * 4 + r) { stot[it][r] -= ev[r]; spos[it][r] -= ev[r]; }
      }
    }
  };

  const int t0 = blockIdx.y * 32;

  // prologue: stage pair 0 (each thread 2x16B, coalesced)
  {
    const short* g = rns + (size_t)t0 * 2048 + threadIdx.x * 8;
    *(short8*)&lbuf[0][threadIdx.x * 8] = *(const short8*)g;
    *(short8*)&lbuf[0][2048 + threadIdx.x * 8] = *(const short8*)(g + 2048);
  }
  __syncthreads();

  for (int p = 0; p < 16; ++p) {
    const int cur = p & 1;
    const int t = t0 + p * 2;
    // T14 split: issue next pair's loads into regs NOW, write to LDS after compute
    short8 nv0, nv1;
    const bool more = (p < 15);
    if (more) {
      const short* g = rns + (size_t)(t + 2) * 2048 + threadIdx.x * 8;
      nv0 = *(const short8*)g;
      nv1 = *(const short8*)(g + 2048);
    }
    const int labj0 = labp[t * 16 + col];
    const int labj1 = labp[t * 16 + 16 + col];

    const short* lb = &lbuf[cur][0];
    short8 b0 = *(const short8*)(lb + lane * 8);
    short8 b1 = *(const short8*)(lb + 512 + lane * 8);
    short8 b2 = *(const short8*)(lb + 1024 + lane * 8);
    short8 b3 = *(const short8*)(lb + 1536 + lane * 8);
    short8 c0 = *(const short8*)(lb + 2048 + lane * 8);
    short8 c1 = *(const short8*)(lb + 2560 + lane * 8);
    short8 c2 = *(const short8*)(lb + 3072 + lane * 8);
    short8 c3 = *(const short8*)(lb + 3584 + lane * 8);

    accum(b0, b1, b2, b3, t, labj0);
    accum(c0, c1, c2, c3, t + 1, labj1);

    if (more) {   // vmcnt wait lands HERE, after ~1200cyc of compute
      *(short8*)&lbuf[cur ^ 1][threadIdx.x * 8] = nv0;
      *(short8*)&lbuf[cur ^ 1][2048 + threadIdx.x * 8] = nv1;
    }
    __syncthreads();
  }

  // tail: y=15 also owns padded tile 512 (rows 8192..8207, never diagonal) —
  // read fragments straight from global (coalesced 1KB, one-time)
  if (blockIdx.y == GY - 1) {
    const short* g = rns + (size_t)512 * 2048 + lane * 8;
    short8 b0 = *(const short8*)(g);
    short8 b1 = *(const short8*)(g + 512);
    short8 b2 = *(const short8*)(g + 1024);
    short8 b3 = *(const short8*)(g + 1536);
    accum(b0, b1, b2, b3, 512, labp[512 * 16 + col]);
  }

  // reduce across the 16 column-lanes, then one atomic per i-row per block
  // (waves own disjoint rows -> no cross-wave reduction needed)
#pragma unroll
  for (int it = 0; it < 2; ++it)
#pragma unroll
    for (int r = 0; r < 4; ++r) {
      float tt = stot[it][r], pp = spos[it][r];
#pragma unroll
      for (int m = 1; m <= 8; m <<= 1) {
        tt += __shfl_xor(tt, m);
        pp += __shfl_xor(pp, m);
      }
      if (col == 0) {
        int i = ibase + (w * 2 + it) * 16 + q * 4 + r;
        atomicAdd(&tot[i], tt);
        atomicAdd(&pos[i], pp);
      }
    }
}

// ---- loss kernel: loss = sum(lv * (lv>0.3)) / (sum(lv>0.3) + eps),
//      lv = -log( ((pos/(tot-9*epad))/(hist[lab]+eps)) + eps )
__global__ __launch_bounds__(1024)
void loss_kernel(const float* __restrict__ tot,
                 const float* __restrict__ pos,
                 const int* __restrict__ labels,
                 float* __restrict__ out) {
  __shared__ int hist[NUM_HIST];
  __shared__ float s1[16], s2[16];
  const int tid = threadIdx.x;
  const int lane = tid & 63, wid = tid >> 6;
  if (tid < NUM_HIST) hist[tid] = 0;
  __syncthreads();
  // ballot-based histogram: 7 ballots per 1024-element stripe, no LDS contention
  int c0 = 0, c1 = 0, c2 = 0, c3 = 0, c4 = 0, c5 = 0, c6 = 0;
  for (int i = tid; i < BN; i += 1024) {
    int lab = labels[i];
    unsigned long long m0 = __ballot(lab == 0);
    unsigned long long m1 = __ballot(lab == 1);
    unsigned long long m2 = __ballot(lab == 2);
    unsigned long long m3 = __ballot(lab == 3);
    unsigned long long m4 = __ballot(lab == 4);
    unsigned long long m5 = __ballot(lab == 5);
    unsigned long long m6 = __ballot(lab == 6);
    if (lane == 0) {
      c0 += __popcll(m0); c1 += __popcll(m1); c2 += __popcll(m2);
      c3 += __popcll(m3); c4 += __popcll(m4); c5 += __popcll(m5);
      c6 += __popcll(m6);
    }
  }
  if (lane == 0) {
    atomicAdd(&hist[0], c0); atomicAdd(&hist[1], c1); atomicAdd(&hist[2], c2);
    atomicAdd(&hist[3], c3); atomicAdd(&hist[4], c4); atomicAdd(&hist[5], c5);
    atomicAdd(&hist[6], c6);
  }
  __syncthreads();
  const float K2 = 10.30496147f;
  const float epad9 = 9.0f * exp2f(-K2);   // padded-column excess in tot
  float lsum = 0.f, msum = 0.f;
  for (int i = tid; i < BN; i += 1024) {
    float t = tot[i] - epad9;
    float p = pos[i];
    float c = (float)hist[labels[i]];   // = sum(pos_mask*mask) exactly
    float pr = (p / t) / (c + 1e-8f);
    float lv = -logf(pr + 1e-8f);
    if (lv > 0.3f) { lsum += lv; msum += 1.f; }
  }
#pragma unroll
  for (int m = 1; m < 64; m <<= 1) {
    lsum += __shfl_xor(lsum, m);
    msum += __shfl_xor(msum, m);
  }
  if (lane == 0) { s1[wid] = lsum; s2[wid] = msum; }
  __syncthreads();
  if (wid == 0) {
    float a = (lane < 16) ? s1[lane] : 0.f;
    float b = (lane < 16) ? s2[lane] : 0.f;
#pragma unroll
    for (int m = 1; m < 16; m <<= 1) {
      a += __shfl_xor(a, m);
      b += __shfl_xor(b, m);
    }
    if (lane == 0) out[0] = a / (b + 1e-8f);
  }
}

extern "C" void kernel_launch(void* const* d_in, const int* in_sizes, int n_in,
                              void* d_out, int out_size, void* d_ws, size_t ws_size,
                              hipStream_t stream) {
  const float* reps    = (const float*)d_in[0];  // [8192,128]
  const int*   labels  = (const int*)d_in[1];    // [8192]
  const float* centers = (const float*)d_in[2];  // [7,256]
  const float* fc_w    = (const float*)d_in[3];  // [128,256]
  const float* fc_b    = (const float*)d_in[4];  // [128]
  float* out = (float*)d_out;

  char* ws = (char*)d_ws;
  int* labp   = (int*)(ws + 4096);                       // 8208*4
  __hip_bfloat16* rnt = (__hip_bfloat16*)(ws + 40960);   // 513 tiles * 4KB = 2101248 B
  float* tot = (float*)(ws + 40960 + 2101248);           // 8192*4
  float* pos = tot + BN;                                 // 8192*4 (contiguous after tot)

  prep_kernel<<<2049, 256, 0, stream>>>(reps, labels, centers, fc_w, fc_b, rnt, labp, tot);
  main_kernel<<<dim3(GX2, GY), 256, 0, stream>>>(rnt, labp, tot, pos);
  loss_kernel<<<1, 1024, 0, stream>>>(tot, pos, labels, out);
}